// Round 15
// baseline (666.785 us; speedup 1.0000x reference)
//
#include <hip/hip_runtime.h>
#include <hip/hip_fp16.h>

#define NN  40000
#define NE  640000
#define ND  128
#define ED  64
#define NH  8
#define DK  16
#define NWT 912   // 384 (q|k|v) + 512 (G composed) + 16 (SB rows, 8 used)

#define SCAN_NBLK 157   // ceil(40000/256)
#define PREP_NBLK 524   // ceil((NWT*ND + ND*ND + NWT)/256)

typedef _Float16 f16x8 __attribute__((ext_vector_type(8)));
typedef float    f32x4 __attribute__((ext_vector_type(4)));

// ---- prep (WT/woT/bias compose) + hist, merged into one launch ----
__global__ __launch_bounds__(256) void k_prep_hist(const float* __restrict__ wq,
                                                   const float* __restrict__ bq,
                                                   const float* __restrict__ wk,
                                                   const float* __restrict__ bk,
                                                   const float* __restrict__ wv,
                                                   const float* __restrict__ bv,
                                                   const float* __restrict__ we,
                                                   const float* __restrict__ be,
                                                   const float* __restrict__ wo,
                                                   const int* __restrict__ ei,
                                                   __half* __restrict__ WT,
                                                   __half* __restrict__ woT,
                                                   float* __restrict__ bias_all,
                                                   int* __restrict__ hist) {
  if (blockIdx.x >= PREP_NBLK) {
    const int e = (blockIdx.x - PREP_NBLK) * 256 + threadIdx.x;
    if (e < NE) atomicAdd(&hist[ei[e]], 1);
    return;
  }
  int idx = blockIdx.x * 256 + threadIdx.x;
  if (idx < NWT * ND) {
    const int n = idx >> 7, k = idx & 127;
    float v;
    if (n < 128)      v = wq[k * ND + n];
    else if (n < 256) v = wk[k * ND + (n - 128)];
    else if (n < 384) v = wv[k * ND + (n - 256)];
    else if (n < 896) {
      const int col = n - 384, h = col >> 6, j = col & 63;
      const float4* a = (const float4*)(wq + (size_t)k * ND + h * DK);
      const float4* b = (const float4*)(we + (size_t)j * ND + h * DK);
      float s = 0.f;
#pragma unroll
      for (int i = 0; i < 4; ++i) {
        float4 av = a[i], bv4 = b[i];
        s = fmaf(av.x, bv4.x, s); s = fmaf(av.y, bv4.y, s);
        s = fmaf(av.z, bv4.z, s); s = fmaf(av.w, bv4.w, s);
      }
      v = 0.25f * s;
    } else if (n < 904) {
      const int h = n - 896;
      const float4* a = (const float4*)(wq + (size_t)k * ND + h * DK);
      const float4* b = (const float4*)(be + h * DK);
      float s = 0.f;
#pragma unroll
      for (int i = 0; i < 4; ++i) {
        float4 av = a[i], bv4 = b[i];
        s = fmaf(av.x, bv4.x, s); s = fmaf(av.y, bv4.y, s);
        s = fmaf(av.z, bv4.z, s); s = fmaf(av.w, bv4.w, s);
      }
      v = 0.25f * s;
    } else v = 0.f;
    WT[idx] = __float2half_rn(v);
    return;
  }
  idx -= NWT * ND;
  if (idx < ND * ND) {
    const int n = idx >> 7, k = idx & 127;
    woT[idx] = __float2half_rn(wo[k * ND + n]);
    return;
  }
  idx -= ND * ND;
  if (idx < NWT) {
    float v;
    if (idx < 128)      v = bq[idx];
    else if (idx < 256) v = bk[idx - 128];
    else if (idx < 384) v = bv[idx - 256];
    else if (idx < 896) {
      const int col = idx - 384, h = col >> 6, j = col & 63;
      const float4* a = (const float4*)(bq + h * DK);
      const float4* b = (const float4*)(we + (size_t)j * ND + h * DK);
      float s = 0.f;
#pragma unroll
      for (int i = 0; i < 4; ++i) {
        float4 av = a[i], bv4 = b[i];
        s = fmaf(av.x, bv4.x, s); s = fmaf(av.y, bv4.y, s);
        s = fmaf(av.z, bv4.z, s); s = fmaf(av.w, bv4.w, s);
      }
      v = 0.25f * s;
    } else if (idx < 904) {
      const int h = idx - 896;
      const float4* a = (const float4*)(bq + h * DK);
      const float4* b = (const float4*)(be + h * DK);
      float s = 0.f;
#pragma unroll
      for (int i = 0; i < 4; ++i) {
        float4 av = a[i], bv4 = b[i];
        s = fmaf(av.x, bv4.x, s); s = fmaf(av.y, bv4.y, s);
        s = fmaf(av.z, bv4.z, s); s = fmaf(av.w, bv4.w, s);
      }
      v = 0.25f * s;
    } else v = 0.f;
    bias_all[idx] = v;
  }
}

// ---- MFMA GEMM 1: x(f32->f16) @ WT^T + bias -> qh|K16|V16, G16, SB ----
__global__ __launch_bounds__(256) void k_gemm1(const float* __restrict__ x,
                                               const __half* __restrict__ WT,
                                               const float* __restrict__ bias_all,
                                               __half* __restrict__ qh,
                                               __half* __restrict__ K16,
                                               __half* __restrict__ V16,
                                               __half* __restrict__ G16,
                                               float* __restrict__ SB) {
  __shared__ _Float16 bs[4][16][132];
  const int wave = threadIdx.x >> 6;
  const int l    = threadIdx.x & 63;
  const int row  = l & 15;
  const int kq   = l >> 4;
  const int r0   = blockIdx.x * 64 + wave * 16;

  f16x8 a[4];
#pragma unroll
  for (int s = 0; s < 4; ++s) {
    const float4* ap = (const float4*)(x + (size_t)(r0 + row) * ND + s * 32 + kq * 8);
    const float4 f0 = ap[0], f1 = ap[1];
    f16x8 t;
    t[0] = (_Float16)f0.x; t[1] = (_Float16)f0.y; t[2] = (_Float16)f0.z; t[3] = (_Float16)f0.w;
    t[4] = (_Float16)f1.x; t[5] = (_Float16)f1.y; t[6] = (_Float16)f1.z; t[7] = (_Float16)f1.w;
    a[s] = t;
  }

  const int rb = r0 + kq * 4;

  for (int nc = 0; nc < 56; nc += 4) {
    __syncthreads();
    {
      const __half* src = WT + (size_t)((nc + wave) * 16 + row) * ND;
      _Float16* dst = &bs[wave][row][0];
#pragma unroll
      for (int ch = 0; ch < 4; ++ch) {
        const int o = (kq + ch * 4) * 8;
        *(f16x8*)(dst + o) = *(const f16x8*)(src + o);
      }
    }
    __syncthreads();
#pragma unroll
    for (int t = 0; t < 4; ++t) {
      const int nt = nc + t;
      f32x4 c = {0.f, 0.f, 0.f, 0.f};
#pragma unroll
      for (int s = 0; s < 4; ++s) {
        const f16x8 b = *(const f16x8*)&bs[t][row][s * 32 + kq * 8];
        c = __builtin_amdgcn_mfma_f32_16x16x32_f16(a[s], b, c, 0, 0, 0);
      }
      const int col = nt * 16 + row;
      const float bb = bias_all[col];
      if (nt < 24) {
        __half* dst = (nt < 8) ? (qh + col) : (nt < 16) ? (K16 + (col - 128)) : (V16 + (col - 256));
#pragma unroll
        for (int i = 0; i < 4; ++i)
          dst[(size_t)(rb + i) * ND] = __float2half_rn(c[i] + bb);
      } else {
        const int gcol = col - 384;
#pragma unroll
        for (int i = 0; i < 4; ++i)
          G16[(size_t)(rb + i) * 512 + gcol] = __float2half_rn(c[i] + bb);
      }
    }
  }

  {
    f32x4 c = {0.f, 0.f, 0.f, 0.f};
#pragma unroll
    for (int s = 0; s < 4; ++s) {
      const f16x8 b = *(const f16x8*)(WT + (size_t)(896 + row) * ND + s * 32 + kq * 8);
      c = __builtin_amdgcn_mfma_f32_16x16x32_f16(a[s], b, c, 0, 0, 0);
    }
    if (row < 8) {
      const float bb = bias_all[896 + row];
#pragma unroll
      for (int i = 0; i < 4; ++i)
        SB[(size_t)(rb + i) * NH + row] = c[i] + bb;
    }
  }
}

// ---- MFMA GEMM 2: mh(f16) @ woT^T + bo -> out(f32); woT fully LDS-staged ----
__global__ __launch_bounds__(256) void k_gemm2(const __half* __restrict__ mh,
                                               const __half* __restrict__ woT,
                                               const float* __restrict__ bo,
                                               float* __restrict__ out) {
  __shared__ _Float16 ws[128][132];
  const int tid  = threadIdx.x;
  const int wave = tid >> 6;
  const int l    = tid & 63;
  const int row  = l & 15;
  const int kq   = l >> 4;
  const int r0   = blockIdx.x * 64 + wave * 16;

  {
    const int r = tid & 127, hf = tid >> 7;
    const __half* src = woT + (size_t)r * ND + hf * 64;
    _Float16* dst = &ws[r][hf * 64];
#pragma unroll
    for (int ch = 0; ch < 8; ++ch)
      *(f16x8*)(dst + ch * 8) = *(const f16x8*)(src + ch * 8);
  }

  f16x8 a[4];
#pragma unroll
  for (int s = 0; s < 4; ++s)
    a[s] = *(const f16x8*)(mh + (size_t)(r0 + row) * ND + s * 32 + kq * 8);

  __syncthreads();

  const int rb = r0 + kq * 4;
#pragma unroll 2
  for (int nt = 0; nt < 8; ++nt) {
    f32x4 c = {0.f, 0.f, 0.f, 0.f};
#pragma unroll
    for (int s = 0; s < 4; ++s) {
      const f16x8 b = *(const f16x8*)&ws[nt * 16 + row][s * 32 + kq * 8];
      c = __builtin_amdgcn_mfma_f32_16x16x32_f16(a[s], b, c, 0, 0, 0);
    }
    const int col = nt * 16 + row;
    const float bb = bo[col];
#pragma unroll
    for (int i = 0; i < 4; ++i)
      out[(size_t)(rb + i) * ND + col] = c[i] + bb;
  }
}

// ---------------- CSR scans + scatter ----------------
__global__ __launch_bounds__(256) void k_scan1(const int* __restrict__ hist,
                                               int* __restrict__ off,
                                               int* __restrict__ bsum) {
  __shared__ int sh[256];
  const int tid = threadIdx.x;
  const int idx = blockIdx.x * 256 + tid;
  int v = (idx < NN) ? hist[idx] : 0;
  sh[tid] = v;
  __syncthreads();
#pragma unroll
  for (int d = 1; d < 256; d <<= 1) {
    int t = (tid >= d) ? sh[tid - d] : 0;
    __syncthreads();
    sh[tid] += t;
    __syncthreads();
  }
  if (idx < NN) off[idx] = sh[tid] - v;
  if (tid == 255) bsum[blockIdx.x] = sh[255];
}

__global__ __launch_bounds__(256) void k_scan2(int* __restrict__ bsum) {
  __shared__ int sh[256];
  const int tid = threadIdx.x;
  int v = (tid < SCAN_NBLK) ? bsum[tid] : 0;
  sh[tid] = v;
  __syncthreads();
#pragma unroll
  for (int d = 1; d < 256; d <<= 1) {
    int t = (tid >= d) ? sh[tid - d] : 0;
    __syncthreads();
    sh[tid] += t;
    __syncthreads();
  }
  if (tid < SCAN_NBLK) bsum[tid] = sh[tid] - v;
}

__global__ __launch_bounds__(256) void k_scan3(int* __restrict__ off,
                                               const int* __restrict__ bsum,
                                               int* __restrict__ cursor) {
  const int idx = blockIdx.x * 256 + threadIdx.x;
  if (idx < NN) {
    int o = off[idx] + bsum[blockIdx.x];
    off[idx] = o;
    cursor[idx] = o;
  }
  if (blockIdx.x == 0 && threadIdx.x == 0) off[NN] = NE;
}

__global__ __launch_bounds__(256) void k_scatter(const int* __restrict__ ei,
                                                 int* __restrict__ cursor,
                                                 int2* __restrict__ pair) {
  int e = blockIdx.x * 256 + threadIdx.x;
  if (e >= NE) return;
  int row = ei[e];
  int col = ei[NE + e];
  int pos = atomicAdd(&cursor[row], 1);
  pair[pos] = make_int2(col, e);
}

// ---------------- fused gather: 1 node / 64-lane wave, dynamic queue ----------
// lane l = (e2<<5)|(h<<2)|q. No LDS: lanes read their own 64B ea q-slice
// directly (8 same-address lanes coalesce/broadcast). Chunk = 8 edges,
// half e2 computes 4 of them in parallel; halves merged by shfl_xor(.,32).
// Work distributed via atomic node counter (load balance across degrees).
#define LOADKV(col, KA, KB, VA, VB) \
  const float2 kr##KA = *(const float2*)(K16 + (size_t)(col) * ND + hq);        \
  const float2 vr##KA = *(const float2*)(V16 + (size_t)(col) * ND + hq);        \
  float2 KA, KB, VA, VB;                                                        \
  { const __half2* _h = (const __half2*)&kr##KA;                                \
    KA = __half22float2(_h[0]); KB = __half22float2(_h[1]); }                   \
  { const __half2* _h = (const __half2*)&vr##KA;                                \
    VA = __half22float2(_h[0]); VB = __half22float2(_h[1]); }

#define EA_ACC(sc, EP) do {                                                    \
  float4 _a;                                                                   \
  _a = (EP)[0];                                                                \
  sc = fmaf(_a.x, gg[0], sc);  sc = fmaf(_a.y, gg[1], sc);                     \
  sc = fmaf(_a.z, gg[2], sc);  sc = fmaf(_a.w, gg[3], sc);                     \
  _a = (EP)[1];                                                                \
  sc = fmaf(_a.x, gg[4], sc);  sc = fmaf(_a.y, gg[5], sc);                     \
  sc = fmaf(_a.z, gg[6], sc);  sc = fmaf(_a.w, gg[7], sc);                     \
  _a = (EP)[2];                                                                \
  sc = fmaf(_a.x, gg[8], sc);  sc = fmaf(_a.y, gg[9], sc);                     \
  sc = fmaf(_a.z, gg[10], sc); sc = fmaf(_a.w, gg[11], sc);                    \
  _a = (EP)[3];                                                                \
  sc = fmaf(_a.x, gg[12], sc); sc = fmaf(_a.y, gg[13], sc);                    \
  sc = fmaf(_a.z, gg[14], sc); sc = fmaf(_a.w, gg[15], sc);                    \
} while (0)

__global__ __launch_bounds__(256) void k_gather(const __half* __restrict__ qh,
                                                const __half* __restrict__ K16,
                                                const __half* __restrict__ V16,
                                                const float* __restrict__ ea,
                                                const int* __restrict__ off,
                                                const int2* __restrict__ pair,
                                                const __half* __restrict__ G16,
                                                const float* __restrict__ SB,
                                                int* __restrict__ nctr,
                                                __half* __restrict__ mh) {
  const int l  = threadIdx.x & 63;
  const int e2 = l >> 5;
  const int h  = (l >> 2) & 7;
  const int q  = l & 3;
  const int hq = h * DK + q * 4;
  const int l8 = l & 7;

  for (;;) {
    int n;
    if (l == 0) n = atomicAdd(nctr, 1);
    n = __shfl(n, 0, 64);
    if (n >= NN) break;

    // ---- per-node setup ----
    float gg[16];
    float4 qv;
    {
      const __half2* qp2 = (const __half2*)(qh + (size_t)n * ND + hq);
      float2 q01 = __half22float2(qp2[0]);
      float2 q23 = __half22float2(qp2[1]);
      qv.x = q01.x * 0.25f; qv.y = q01.y * 0.25f;
      qv.z = q23.x * 0.25f; qv.w = q23.y * 0.25f;
    }
    const float sb = SB[n * NH + h];
    {
      const float4* gp = (const float4*)(G16 + (size_t)n * 512 + h * 64 + q * 16);
      float4 c0 = gp[0], c1 = gp[1];
      const __half2* h0 = (const __half2*)&c0;
      const __half2* h1 = (const __half2*)&c1;
#pragma unroll
      for (int i = 0; i < 4; ++i) {
        float2 f0 = __half22float2(h0[i]);
        gg[2 * i + 0] = f0.x; gg[2 * i + 1] = f0.y;
        float2 f1 = __half22float2(h1[i]);
        gg[8 + 2 * i + 0] = f1.x; gg[8 + 2 * i + 1] = f1.y;
      }
    }

    float4 acc = make_float4(0.f, 0.f, 0.f, 0.f);
    float den = 0.f;

    const int j0 = off[n], j1 = off[n + 1];
    const int jlast = j1 - 1;

    if (j0 < j1) {
      int2 p = pair[min(j0 + l8, jlast)];
      for (int jp = j0; jp < j1; jp += 8) {
        const int2 pn = pair[min(jp + 8 + l8, jlast)];

        // this half's 4 edges
        const int eb = e2 * 4;
        const int col0 = __shfl(p.x, eb + 0, 32);
        const int col1 = __shfl(p.x, eb + 1, 32);
        const int col2 = __shfl(p.x, eb + 2, 32);
        const int col3 = __shfl(p.x, eb + 3, 32);
        const int eid0 = __shfl(p.y, eb + 0, 32);
        const int eid1 = __shfl(p.y, eb + 1, 32);
        const int eid2 = __shfl(p.y, eb + 2, 32);
        const int eid3 = __shfl(p.y, eb + 3, 32);

        LOADKV(col0, ka0, kb0, va0, vb0);
        LOADKV(col1, ka1, kb1, va1, vb1);
        LOADKV(col2, ka2, kb2, va2, vb2);
        LOADKV(col3, ka3, kb3, va3, vb3);

        const float4* E0 = (const float4*)(ea + (size_t)eid0 * ED + q * 16);
        const float4* E1 = (const float4*)(ea + (size_t)eid1 * ED + q * 16);
        const float4* E2 = (const float4*)(ea + (size_t)eid2 * ED + q * 16);
        const float4* E3 = (const float4*)(ea + (size_t)eid3 * ED + q * 16);

        float s0 = ka0.x * qv.x; s0 = fmaf(qv.y, ka0.y, s0); s0 = fmaf(qv.z, kb0.x, s0); s0 = fmaf(qv.w, kb0.y, s0);
        float s1 = ka1.x * qv.x; s1 = fmaf(qv.y, ka1.y, s1); s1 = fmaf(qv.z, kb1.x, s1); s1 = fmaf(qv.w, kb1.y, s1);
        float s2 = ka2.x * qv.x; s2 = fmaf(qv.y, ka2.y, s2); s2 = fmaf(qv.z, kb2.x, s2); s2 = fmaf(qv.w, kb2.y, s2);
        float s3 = ka3.x * qv.x; s3 = fmaf(qv.y, ka3.y, s3); s3 = fmaf(qv.z, kb3.x, s3); s3 = fmaf(qv.w, kb3.y, s3);

        EA_ACC(s0, E0); EA_ACC(s1, E1); EA_ACC(s2, E2); EA_ACC(s3, E3);

        s0 += __shfl_xor(s0, 1); s0 += __shfl_xor(s0, 2);
        s1 += __shfl_xor(s1, 1); s1 += __shfl_xor(s1, 2);
        s2 += __shfl_xor(s2, 1); s2 += __shfl_xor(s2, 2);
        s3 += __shfl_xor(s3, 1); s3 += __shfl_xor(s3, 2);

        const int ebase = jp + eb;
        const float es0 = (ebase + 0 < j1) ? __expf(s0 + sb) : 0.f;
        const float es1 = (ebase + 1 < j1) ? __expf(s1 + sb) : 0.f;
        const float es2 = (ebase + 2 < j1) ? __expf(s2 + sb) : 0.f;
        const float es3 = (ebase + 3 < j1) ? __expf(s3 + sb) : 0.f;
        den += (es0 + es1) + (es2 + es3);

        acc.x = fmaf(es0, va0.x, acc.x); acc.y = fmaf(es0, va0.y, acc.y);
        acc.z = fmaf(es0, vb0.x, acc.z); acc.w = fmaf(es0, vb0.y, acc.w);
        acc.x = fmaf(es1, va1.x, acc.x); acc.y = fmaf(es1, va1.y, acc.y);
        acc.z = fmaf(es1, vb1.x, acc.z); acc.w = fmaf(es1, vb1.y, acc.w);
        acc.x = fmaf(es2, va2.x, acc.x); acc.y = fmaf(es2, va2.y, acc.y);
        acc.z = fmaf(es2, vb2.x, acc.z); acc.w = fmaf(es2, vb2.y, acc.w);
        acc.x = fmaf(es3, va3.x, acc.x); acc.y = fmaf(es3, va3.y, acc.y);
        acc.z = fmaf(es3, vb3.x, acc.z); acc.w = fmaf(es3, vb3.y, acc.w);

        p = pn;
      }
    }

    // merge halves
    den   += __shfl_xor(den, 32);
    acc.x += __shfl_xor(acc.x, 32);
    acc.y += __shfl_xor(acc.y, 32);
    acc.z += __shfl_xor(acc.z, 32);
    acc.w += __shfl_xor(acc.w, 32);

    if (e2 == 0) {
      const float inv = 1.f / (den + 1e-8f);
      union { __half2 h2[2]; float2 f; } u;
      u.h2[0] = __floats2half2_rn(acc.x * inv, acc.y * inv);
      u.h2[1] = __floats2half2_rn(acc.z * inv, acc.w * inv);
      *(float2*)(mh + (size_t)n * ND + hq) = u.f;
    }
  }
}

extern "C" void kernel_launch(void* const* d_in, const int* in_sizes, int n_in,
                              void* d_out, int out_size, void* d_ws, size_t ws_size,
                              hipStream_t stream) {
  const float* nodes = (const float*)d_in[0];
  const int*   ei    = (const int*)d_in[1];
  const float* ea    = (const float*)d_in[2];
  const float* wq    = (const float*)d_in[3];
  const float* bq    = (const float*)d_in[4];
  const float* wk    = (const float*)d_in[5];
  const float* bk    = (const float*)d_in[6];
  const float* wv    = (const float*)d_in[7];
  const float* bv    = (const float*)d_in[8];
  const float* we    = (const float*)d_in[9];
  const float* be    = (const float*)d_in[10];
  const float* wo    = (const float*)d_in[11];
  const float* bo    = (const float*)d_in[12];
  float* out = (float*)d_out;

  const size_t NND = (size_t)NN * ND;
  __half* qh   = (__half*)d_ws;              // NND
  __half* K16  = qh + NND;                   // NND
  __half* V16  = K16 + NND;                  // NND
  __half* mh   = V16 + NND;                  // NND
  __half* G16  = mh + NND;                   // NN*512
  __half* WT   = G16 + (size_t)NN * 512;     // 912*128
  __half* woT  = WT + (size_t)NWT * ND;      // 128*128
  float* SB    = (float*)(woT + ND * ND);    // NN*8
  float* bias_all = SB + (size_t)NN * NH;    // NWT
  int* hist    = (int*)(bias_all + NWT);     // NN
  int* off     = hist + NN;                  // 40004
  int* cursor  = off + 40004;                // NN
  int* bsum    = cursor + NN;                // 256
  int* nctr    = bsum + 256;                 // 4 (pad to keep pair 8B-aligned)
  int2* pair   = (int2*)(nctr + 4);          // NE

  hipMemsetAsync(hist, 0, NN * sizeof(int), stream);
  hipMemsetAsync(nctr, 0, sizeof(int), stream);

  dim3 blk(256);

  k_prep_hist<<<dim3(PREP_NBLK + (NE + 255) / 256), blk, 0, stream>>>(
      wq, bq, wk, bk, wv, bv, we, be, wo, ei, WT, woT, bias_all, hist);

  k_gemm1<<<dim3(NN / 64), blk, 0, stream>>>(nodes, WT, bias_all, qh, K16, V16, G16, SB);

  k_scan1<<<dim3(SCAN_NBLK), blk, 0, stream>>>(hist, off, bsum);
  k_scan2<<<dim3(1), blk, 0, stream>>>(bsum);
  k_scan3<<<dim3(SCAN_NBLK), blk, 0, stream>>>(off, bsum, cursor);
  dim3 gE((NE + 255) / 256);
  k_scatter<<<gE, blk, 0, stream>>>(ei, cursor, pair);

  k_gather<<<dim3(1024), blk, 0, stream>>>(qh, K16, V16, ea, off, pair, G16, SB, nctr, mh);

  k_gemm2<<<dim3(NN / 64), blk, 0, stream>>>(mh, woT, bo, out);
}

// Round 16
// 226.243 us; speedup vs baseline: 2.9472x; 2.9472x over previous
//
#include <hip/hip_runtime.h>
#include <hip/hip_fp16.h>

#define NN  40000
#define NE  640000
#define ND  128
#define ED  64
#define NH  8
#define DK  16
#define NWT 912   // 384 (q|k|v) + 512 (G composed) + 16 (SB rows, 8 used)

#define SCAN_NBLK 157   // ceil(40000/256)
#define PREP_NBLK 524   // ceil((NWT*ND + ND*ND + NWT)/256)

typedef _Float16 f16x8 __attribute__((ext_vector_type(8)));
typedef float    f32x4 __attribute__((ext_vector_type(4)));

// ---- prep (WT/woT/bias compose) + hist, merged into one launch ----
__global__ __launch_bounds__(256) void k_prep_hist(const float* __restrict__ wq,
                                                   const float* __restrict__ bq,
                                                   const float* __restrict__ wk,
                                                   const float* __restrict__ bk,
                                                   const float* __restrict__ wv,
                                                   const float* __restrict__ bv,
                                                   const float* __restrict__ we,
                                                   const float* __restrict__ be,
                                                   const float* __restrict__ wo,
                                                   const int* __restrict__ ei,
                                                   __half* __restrict__ WT,
                                                   __half* __restrict__ woT,
                                                   float* __restrict__ bias_all,
                                                   int* __restrict__ hist) {
  if (blockIdx.x >= PREP_NBLK) {
    const int e = (blockIdx.x - PREP_NBLK) * 256 + threadIdx.x;
    if (e < NE) atomicAdd(&hist[ei[e]], 1);
    return;
  }
  int idx = blockIdx.x * 256 + threadIdx.x;
  if (idx < NWT * ND) {
    const int n = idx >> 7, k = idx & 127;
    float v;
    if (n < 128)      v = wq[k * ND + n];
    else if (n < 256) v = wk[k * ND + (n - 128)];
    else if (n < 384) v = wv[k * ND + (n - 256)];
    else if (n < 896) {
      const int col = n - 384, h = col >> 6, j = col & 63;
      const float4* a = (const float4*)(wq + (size_t)k * ND + h * DK);
      const float4* b = (const float4*)(we + (size_t)j * ND + h * DK);
      float s = 0.f;
#pragma unroll
      for (int i = 0; i < 4; ++i) {
        float4 av = a[i], bv4 = b[i];
        s = fmaf(av.x, bv4.x, s); s = fmaf(av.y, bv4.y, s);
        s = fmaf(av.z, bv4.z, s); s = fmaf(av.w, bv4.w, s);
      }
      v = 0.25f * s;
    } else if (n < 904) {
      const int h = n - 896;
      const float4* a = (const float4*)(wq + (size_t)k * ND + h * DK);
      const float4* b = (const float4*)(be + h * DK);
      float s = 0.f;
#pragma unroll
      for (int i = 0; i < 4; ++i) {
        float4 av = a[i], bv4 = b[i];
        s = fmaf(av.x, bv4.x, s); s = fmaf(av.y, bv4.y, s);
        s = fmaf(av.z, bv4.z, s); s = fmaf(av.w, bv4.w, s);
      }
      v = 0.25f * s;
    } else v = 0.f;
    WT[idx] = __float2half_rn(v);
    return;
  }
  idx -= NWT * ND;
  if (idx < ND * ND) {
    const int n = idx >> 7, k = idx & 127;
    woT[idx] = __float2half_rn(wo[k * ND + n]);
    return;
  }
  idx -= ND * ND;
  if (idx < NWT) {
    float v;
    if (idx < 128)      v = bq[idx];
    else if (idx < 256) v = bk[idx - 128];
    else if (idx < 384) v = bv[idx - 256];
    else if (idx < 896) {
      const int col = idx - 384, h = col >> 6, j = col & 63;
      const float4* a = (const float4*)(bq + h * DK);
      const float4* b = (const float4*)(we + (size_t)j * ND + h * DK);
      float s = 0.f;
#pragma unroll
      for (int i = 0; i < 4; ++i) {
        float4 av = a[i], bv4 = b[i];
        s = fmaf(av.x, bv4.x, s); s = fmaf(av.y, bv4.y, s);
        s = fmaf(av.z, bv4.z, s); s = fmaf(av.w, bv4.w, s);
      }
      v = 0.25f * s;
    } else if (idx < 904) {
      const int h = idx - 896;
      const float4* a = (const float4*)(bq + h * DK);
      const float4* b = (const float4*)(be + h * DK);
      float s = 0.f;
#pragma unroll
      for (int i = 0; i < 4; ++i) {
        float4 av = a[i], bv4 = b[i];
        s = fmaf(av.x, bv4.x, s); s = fmaf(av.y, bv4.y, s);
        s = fmaf(av.z, bv4.z, s); s = fmaf(av.w, bv4.w, s);
      }
      v = 0.25f * s;
    } else v = 0.f;
    bias_all[idx] = v;
  }
}

// ---- MFMA GEMM 1: x(f32->f16) @ WT^T + bias -> qh|K16|V16, G16, SB ----
__global__ __launch_bounds__(256) void k_gemm1(const float* __restrict__ x,
                                               const __half* __restrict__ WT,
                                               const float* __restrict__ bias_all,
                                               __half* __restrict__ qh,
                                               __half* __restrict__ K16,
                                               __half* __restrict__ V16,
                                               __half* __restrict__ G16,
                                               float* __restrict__ SB) {
  __shared__ _Float16 bs[4][16][132];
  const int wave = threadIdx.x >> 6;
  const int l    = threadIdx.x & 63;
  const int row  = l & 15;
  const int kq   = l >> 4;
  const int r0   = blockIdx.x * 64 + wave * 16;

  f16x8 a[4];
#pragma unroll
  for (int s = 0; s < 4; ++s) {
    const float4* ap = (const float4*)(x + (size_t)(r0 + row) * ND + s * 32 + kq * 8);
    const float4 f0 = ap[0], f1 = ap[1];
    f16x8 t;
    t[0] = (_Float16)f0.x; t[1] = (_Float16)f0.y; t[2] = (_Float16)f0.z; t[3] = (_Float16)f0.w;
    t[4] = (_Float16)f1.x; t[5] = (_Float16)f1.y; t[6] = (_Float16)f1.z; t[7] = (_Float16)f1.w;
    a[s] = t;
  }

  const int rb = r0 + kq * 4;

  for (int nc = 0; nc < 56; nc += 4) {
    __syncthreads();
    {
      const __half* src = WT + (size_t)((nc + wave) * 16 + row) * ND;
      _Float16* dst = &bs[wave][row][0];
#pragma unroll
      for (int ch = 0; ch < 4; ++ch) {
        const int o = (kq + ch * 4) * 8;
        *(f16x8*)(dst + o) = *(const f16x8*)(src + o);
      }
    }
    __syncthreads();
#pragma unroll
    for (int t = 0; t < 4; ++t) {
      const int nt = nc + t;
      f32x4 c = {0.f, 0.f, 0.f, 0.f};
#pragma unroll
      for (int s = 0; s < 4; ++s) {
        const f16x8 b = *(const f16x8*)&bs[t][row][s * 32 + kq * 8];
        c = __builtin_amdgcn_mfma_f32_16x16x32_f16(a[s], b, c, 0, 0, 0);
      }
      const int col = nt * 16 + row;
      const float bb = bias_all[col];
      if (nt < 24) {
        __half* dst = (nt < 8) ? (qh + col) : (nt < 16) ? (K16 + (col - 128)) : (V16 + (col - 256));
#pragma unroll
        for (int i = 0; i < 4; ++i)
          dst[(size_t)(rb + i) * ND] = __float2half_rn(c[i] + bb);
      } else {
        const int gcol = col - 384;
#pragma unroll
        for (int i = 0; i < 4; ++i)
          G16[(size_t)(rb + i) * 512 + gcol] = __float2half_rn(c[i] + bb);
      }
    }
  }

  {
    f32x4 c = {0.f, 0.f, 0.f, 0.f};
#pragma unroll
    for (int s = 0; s < 4; ++s) {
      const f16x8 b = *(const f16x8*)(WT + (size_t)(896 + row) * ND + s * 32 + kq * 8);
      c = __builtin_amdgcn_mfma_f32_16x16x32_f16(a[s], b, c, 0, 0, 0);
    }
    if (row < 8) {
      const float bb = bias_all[896 + row];
#pragma unroll
      for (int i = 0; i < 4; ++i)
        SB[(size_t)(rb + i) * NH + row] = c[i] + bb;
    }
  }
}

// ---- MFMA GEMM 2: mh(f16) @ woT^T + bo -> out(f32); woT fully LDS-staged ----
__global__ __launch_bounds__(256) void k_gemm2(const __half* __restrict__ mh,
                                               const __half* __restrict__ woT,
                                               const float* __restrict__ bo,
                                               float* __restrict__ out) {
  __shared__ _Float16 ws[128][132];
  const int tid  = threadIdx.x;
  const int wave = tid >> 6;
  const int l    = tid & 63;
  const int row  = l & 15;
  const int kq   = l >> 4;
  const int r0   = blockIdx.x * 64 + wave * 16;

  {
    const int r = tid & 127, hf = tid >> 7;
    const __half* src = woT + (size_t)r * ND + hf * 64;
    _Float16* dst = &ws[r][hf * 64];
#pragma unroll
    for (int ch = 0; ch < 8; ++ch)
      *(f16x8*)(dst + ch * 8) = *(const f16x8*)(src + ch * 8);
  }

  f16x8 a[4];
#pragma unroll
  for (int s = 0; s < 4; ++s)
    a[s] = *(const f16x8*)(mh + (size_t)(r0 + row) * ND + s * 32 + kq * 8);

  __syncthreads();

  const int rb = r0 + kq * 4;
#pragma unroll 2
  for (int nt = 0; nt < 8; ++nt) {
    f32x4 c = {0.f, 0.f, 0.f, 0.f};
#pragma unroll
    for (int s = 0; s < 4; ++s) {
      const f16x8 b = *(const f16x8*)&ws[nt * 16 + row][s * 32 + kq * 8];
      c = __builtin_amdgcn_mfma_f32_16x16x32_f16(a[s], b, c, 0, 0, 0);
    }
    const int col = nt * 16 + row;
    const float bb = bo[col];
#pragma unroll
    for (int i = 0; i < 4; ++i)
      out[(size_t)(rb + i) * ND + col] = c[i] + bb;
  }
}

// ---------------- CSR scans + scatter ----------------
__global__ __launch_bounds__(256) void k_scan1(const int* __restrict__ hist,
                                               int* __restrict__ off,
                                               int* __restrict__ bsum) {
  __shared__ int sh[256];
  const int tid = threadIdx.x;
  const int idx = blockIdx.x * 256 + tid;
  int v = (idx < NN) ? hist[idx] : 0;
  sh[tid] = v;
  __syncthreads();
#pragma unroll
  for (int d = 1; d < 256; d <<= 1) {
    int t = (tid >= d) ? sh[tid - d] : 0;
    __syncthreads();
    sh[tid] += t;
    __syncthreads();
  }
  if (idx < NN) off[idx] = sh[tid] - v;
  if (tid == 255) bsum[blockIdx.x] = sh[255];
}

__global__ __launch_bounds__(256) void k_scan2(int* __restrict__ bsum) {
  __shared__ int sh[256];
  const int tid = threadIdx.x;
  int v = (tid < SCAN_NBLK) ? bsum[tid] : 0;
  sh[tid] = v;
  __syncthreads();
#pragma unroll
  for (int d = 1; d < 256; d <<= 1) {
    int t = (tid >= d) ? sh[tid - d] : 0;
    __syncthreads();
    sh[tid] += t;
    __syncthreads();
  }
  if (tid < SCAN_NBLK) bsum[tid] = sh[tid] - v;
}

__global__ __launch_bounds__(256) void k_scan3(int* __restrict__ off,
                                               const int* __restrict__ bsum,
                                               int* __restrict__ cursor) {
  const int idx = blockIdx.x * 256 + threadIdx.x;
  if (idx < NN) {
    int o = off[idx] + bsum[blockIdx.x];
    off[idx] = o;
    cursor[idx] = o;
  }
  if (blockIdx.x == 0 && threadIdx.x == 0) off[NN] = NE;
}

__global__ __launch_bounds__(256) void k_scatter(const int* __restrict__ ei,
                                                 int* __restrict__ cursor,
                                                 int2* __restrict__ pair) {
  int e = blockIdx.x * 256 + threadIdx.x;
  if (e >= NE) return;
  int row = ei[e];
  int col = ei[NE + e];
  int pos = atomicAdd(&cursor[row], 1);
  pair[pos] = make_int2(col, e);
}

// ---------------- fused gather: 1 node / 64-lane wave, R14 pipeline -----------
// lane l = (e2<<5)|(h<<2)|q. Chunk = 16 edges; half e2 computes its 8.
// Pipeline identical to R14: ds_write ea(t) from regs; prefetch ea(t+1)->regs
// + pair(t+2); one lgkmcnt(0) per chunk; all prefetch indices clamped to jlast.
#define LOADKV(col, KA, KB, VA, VB) \
  const float2 kr##KA = *(const float2*)(K16 + (size_t)(col) * ND + hq);        \
  const float2 vr##KA = *(const float2*)(V16 + (size_t)(col) * ND + hq);        \
  float2 KA, KB, VA, VB;                                                        \
  { const __half2* _h = (const __half2*)&kr##KA;                                \
    KA = __half22float2(_h[0]); KB = __half22float2(_h[1]); }                   \
  { const __half2* _h = (const __half2*)&vr##KA;                                \
    VA = __half22float2(_h[0]); VB = __half22float2(_h[1]); }

__global__ __launch_bounds__(256) void k_gather(const __half* __restrict__ qh,
                                                const __half* __restrict__ K16,
                                                const __half* __restrict__ V16,
                                                const float* __restrict__ ea,
                                                const int* __restrict__ off,
                                                const int2* __restrict__ pair,
                                                const __half* __restrict__ G16,
                                                const float* __restrict__ SB,
                                                __half* __restrict__ mh) {
  __shared__ float eas[4][16 * ED];   // 4 waves x 16 edges x 64 floats = 16 KB
  const int w  = threadIdx.x >> 6;
  const int n  = blockIdx.x * 4 + w;
  const int l  = threadIdx.x & 63;
  const int e2 = l >> 5;
  const int h  = (l >> 2) & 7;
  const int q  = l & 3;
  const int hq = h * DK + q * 4;
  const int l16 = l & 15;
  const int se  = l >> 2;   // staging edge 0..15
  const int sp  = l & 3;    // staging float4-part

  float gg[16];
  float4 qv;
  {
    const __half2* qp2 = (const __half2*)(qh + (size_t)n * ND + hq);
    float2 q01 = __half22float2(qp2[0]);
    float2 q23 = __half22float2(qp2[1]);
    qv.x = q01.x * 0.25f; qv.y = q01.y * 0.25f;
    qv.z = q23.x * 0.25f; qv.w = q23.y * 0.25f;
  }
  const float sb = SB[n * NH + h];
  {
    const float4* gp = (const float4*)(G16 + (size_t)n * 512 + h * 64 + q * 16);
    float4 c0 = gp[0], c1 = gp[1];
    const __half2* h0 = (const __half2*)&c0;
    const __half2* h1 = (const __half2*)&c1;
#pragma unroll
    for (int i = 0; i < 4; ++i) {
      float2 f0 = __half22float2(h0[i]);
      gg[2 * i + 0] = f0.x; gg[2 * i + 1] = f0.y;
      float2 f1 = __half22float2(h1[i]);
      gg[8 + 2 * i + 0] = f1.x; gg[8 + 2 * i + 1] = f1.y;
    }
  }

  float4 acc = make_float4(0.f, 0.f, 0.f, 0.f);
  float den = 0.f;

  const int j0 = off[n], j1 = off[n + 1];
  const int jlast = j1 - 1;

  if (j0 < j1) {
    int2 p = pair[min(j0 + l16, jlast)];
    float4 er0, er1, er2, er3;
    {
      const int eid = __shfl(p.y, se, 64);
      const float4* s4 = (const float4*)(ea + (size_t)eid * ED) + sp;
      er0 = s4[0]; er1 = s4[4]; er2 = s4[8]; er3 = s4[12];
    }
    int2 pn = pair[min(j0 + 16 + l16, jlast)];

    for (int jp = j0; jp < j1; jp += 16) {
      // 1. ds_write ea(t)
      {
        float* d = &eas[w][se * ED] + sp * 4;
        *(float4*)(d + 0)  = er0; *(float4*)(d + 16) = er1;
        *(float4*)(d + 32) = er2; *(float4*)(d + 48) = er3;
      }
      // 2/3. prefetch ea(t+1) regs + pair(t+2)
      int2 pf = pn;
      if (jp + 16 < j1) {
        const int eidN = __shfl(pn.y, se, 64);
        const float4* s4 = (const float4*)(ea + (size_t)eidN * ED) + sp;
        er0 = s4[0]; er1 = s4[4]; er2 = s4[8]; er3 = s4[12];
        pf = pair[min(jp + 32 + l16, jlast)];
      }
      // 4. staging visible (wave-local LDS)
      asm volatile("s_waitcnt lgkmcnt(0)" ::: "memory");
      __builtin_amdgcn_sched_barrier(0);

      // 5. compute this half's 8 edges (2 groups of 4)
      const int eb = e2 * 8;
#pragma unroll
      for (int cb = 0; cb < 8; cb += 4) {
        const int col0 = __shfl(p.x, eb + cb + 0, 64);
        const int col1 = __shfl(p.x, eb + cb + 1, 64);
        const int col2 = __shfl(p.x, eb + cb + 2, 64);
        const int col3 = __shfl(p.x, eb + cb + 3, 64);

        LOADKV(col0, ka0, kb0, va0, vb0);
        LOADKV(col1, ka1, kb1, va1, vb1);
        LOADKV(col2, ka2, kb2, va2, vb2);
        LOADKV(col3, ka3, kb3, va3, vb3);

        float s0 = ka0.x * qv.x; s0 = fmaf(qv.y, ka0.y, s0); s0 = fmaf(qv.z, kb0.x, s0); s0 = fmaf(qv.w, kb0.y, s0);
        float s1 = ka1.x * qv.x; s1 = fmaf(qv.y, ka1.y, s1); s1 = fmaf(qv.z, kb1.x, s1); s1 = fmaf(qv.w, kb1.y, s1);
        float s2 = ka2.x * qv.x; s2 = fmaf(qv.y, ka2.y, s2); s2 = fmaf(qv.z, kb2.x, s2); s2 = fmaf(qv.w, kb2.y, s2);
        float s3 = ka3.x * qv.x; s3 = fmaf(qv.y, ka3.y, s3); s3 = fmaf(qv.z, kb3.x, s3); s3 = fmaf(qv.w, kb3.y, s3);

        const float4* e0 = (const float4*)&eas[w][(eb + cb + 0) * ED + q * 16];
        const float4* e1 = (const float4*)&eas[w][(eb + cb + 1) * ED + q * 16];
        const float4* e2p = (const float4*)&eas[w][(eb + cb + 2) * ED + q * 16];
        const float4* e3 = (const float4*)&eas[w][(eb + cb + 3) * ED + q * 16];
#pragma unroll
        for (int i = 0; i < 4; ++i) {
          float4 a = e0[i];
          s0 = fmaf(a.x, gg[4 * i + 0], s0); s0 = fmaf(a.y, gg[4 * i + 1], s0);
          s0 = fmaf(a.z, gg[4 * i + 2], s0); s0 = fmaf(a.w, gg[4 * i + 3], s0);
        }
#pragma unroll
        for (int i = 0; i < 4; ++i) {
          float4 a = e1[i];
          s1 = fmaf(a.x, gg[4 * i + 0], s1); s1 = fmaf(a.y, gg[4 * i + 1], s1);
          s1 = fmaf(a.z, gg[4 * i + 2], s1); s1 = fmaf(a.w, gg[4 * i + 3], s1);
        }
#pragma unroll
        for (int i = 0; i < 4; ++i) {
          float4 a = e2p[i];
          s2 = fmaf(a.x, gg[4 * i + 0], s2); s2 = fmaf(a.y, gg[4 * i + 1], s2);
          s2 = fmaf(a.z, gg[4 * i + 2], s2); s2 = fmaf(a.w, gg[4 * i + 3], s2);
        }
#pragma unroll
        for (int i = 0; i < 4; ++i) {
          float4 a = e3[i];
          s3 = fmaf(a.x, gg[4 * i + 0], s3); s3 = fmaf(a.y, gg[4 * i + 1], s3);
          s3 = fmaf(a.z, gg[4 * i + 2], s3); s3 = fmaf(a.w, gg[4 * i + 3], s3);
        }

        s0 += __shfl_xor(s0, 1); s0 += __shfl_xor(s0, 2);
        s1 += __shfl_xor(s1, 1); s1 += __shfl_xor(s1, 2);
        s2 += __shfl_xor(s2, 1); s2 += __shfl_xor(s2, 2);
        s3 += __shfl_xor(s3, 1); s3 += __shfl_xor(s3, 2);

        const int ebase = jp + eb + cb;
        const float es0 = (ebase + 0 < j1) ? __expf(s0 + sb) : 0.f;
        const float es1 = (ebase + 1 < j1) ? __expf(s1 + sb) : 0.f;
        const float es2 = (ebase + 2 < j1) ? __expf(s2 + sb) : 0.f;
        const float es3 = (ebase + 3 < j1) ? __expf(s3 + sb) : 0.f;
        den += (es0 + es1) + (es2 + es3);

        acc.x = fmaf(es0, va0.x, acc.x); acc.y = fmaf(es0, va0.y, acc.y);
        acc.z = fmaf(es0, vb0.x, acc.z); acc.w = fmaf(es0, vb0.y, acc.w);
        acc.x = fmaf(es1, va1.x, acc.x); acc.y = fmaf(es1, va1.y, acc.y);
        acc.z = fmaf(es1, vb1.x, acc.z); acc.w = fmaf(es1, vb1.y, acc.w);
        acc.x = fmaf(es2, va2.x, acc.x); acc.y = fmaf(es2, va2.y, acc.y);
        acc.z = fmaf(es2, vb2.x, acc.z); acc.w = fmaf(es2, vb2.y, acc.w);
        acc.x = fmaf(es3, va3.x, acc.x); acc.y = fmaf(es3, va3.y, acc.y);
        acc.z = fmaf(es3, vb3.x, acc.z); acc.w = fmaf(es3, vb3.y, acc.w);
      }

      p = pn; pn = pf;
    }
  }

  // merge halves
  den   += __shfl_xor(den, 32);
  acc.x += __shfl_xor(acc.x, 32);
  acc.y += __shfl_xor(acc.y, 32);
  acc.z += __shfl_xor(acc.z, 32);
  acc.w += __shfl_xor(acc.w, 32);

  if (e2 == 0) {
    const float inv = 1.f / (den + 1e-8f);
    union { __half2 h2[2]; float2 f; } u;
    u.h2[0] = __floats2half2_rn(acc.x * inv, acc.y * inv);
    u.h2[1] = __floats2half2_rn(acc.z * inv, acc.w * inv);
    *(float2*)(mh + (size_t)n * ND + hq) = u.f;
  }
}

extern "C" void kernel_launch(void* const* d_in, const int* in_sizes, int n_in,
                              void* d_out, int out_size, void* d_ws, size_t ws_size,
                              hipStream_t stream) {
  const float* nodes = (const float*)d_in[0];
  const int*   ei    = (const int*)d_in[1];
  const float* ea    = (const float*)d_in[2];
  const float* wq    = (const float*)d_in[3];
  const float* bq    = (const float*)d_in[4];
  const float* wk    = (const float*)d_in[5];
  const float* bk    = (const float*)d_in[6];
  const float* wv    = (const float*)d_in[7];
  const float* bv    = (const float*)d_in[8];
  const float* we    = (const float*)d_in[9];
  const float* be    = (const float*)d_in[10];
  const float* wo    = (const float*)d_in[11];
  const float* bo    = (const float*)d_in[12];
  float* out = (float*)d_out;

  const size_t NND = (size_t)NN * ND;
  __half* qh   = (__half*)d_ws;              // NND
  __half* K16  = qh + NND;                   // NND
  __half* V16  = K16 + NND;                  // NND
  __half* mh   = V16 + NND;                  // NND
  __half* G16  = mh + NND;                   // NN*512
  __half* WT   = G16 + (size_t)NN * 512;     // 912*128
  __half* woT  = WT + (size_t)NWT * ND;      // 128*128
  float* SB    = (float*)(woT + ND * ND);    // NN*8
  float* bias_all = SB + (size_t)NN * NH;    // NWT
  int* hist    = (int*)(bias_all + NWT);     // NN
  int* off     = hist + NN;                  // 40004
  int* cursor  = off + 40004;                // NN
  int* bsum    = cursor + NN;                // 256
  int2* pair   = (int2*)(bsum + 256);        // NE

  hipMemsetAsync(hist, 0, NN * sizeof(int), stream);

  dim3 blk(256);

  k_prep_hist<<<dim3(PREP_NBLK + (NE + 255) / 256), blk, 0, stream>>>(
      wq, bq, wk, bk, wv, bv, we, be, wo, ei, WT, woT, bias_all, hist);

  k_gemm1<<<dim3(NN / 64), blk, 0, stream>>>(nodes, WT, bias_all, qh, K16, V16, G16, SB);

  k_scan1<<<dim3(SCAN_NBLK), blk, 0, stream>>>(hist, off, bsum);
  k_scan2<<<dim3(1), blk, 0, stream>>>(bsum);
  k_scan3<<<dim3(SCAN_NBLK), blk, 0, stream>>>(off, bsum, cursor);
  dim3 gE((NE + 255) / 256);
  k_scatter<<<gE, blk, 0, stream>>>(ei, cursor, pair);

  k_gather<<<dim3(NN / 4), blk, 0, stream>>>(qh, K16, V16, ea, off, pair, G16, SB, mh);

  k_gemm2<<<dim3(NN / 64), blk, 0, stream>>>(mh, woT, bo, out);
}

// Round 17
// 209.329 us; speedup vs baseline: 3.1854x; 1.0808x over previous
//
#include <hip/hip_runtime.h>
#include <hip/hip_fp16.h>

#define NN  40000
#define NE  640000
#define ND  128
#define ED  64
#define NH  8
#define DK  16
#define NWT 912   // 384 (q|k|v) + 512 (G composed) + 16 (SB rows, 8 used)

#define SCAN_NBLK 157   // ceil(40000/256)
#define PREP_NBLK 524   // ceil((NWT*ND + ND*ND + NWT)/256)

typedef _Float16 f16x8 __attribute__((ext_vector_type(8)));
typedef float    f32x4 __attribute__((ext_vector_type(4)));

// ---- prep (WT/woT/bias compose) + hist, merged into one launch ----
__global__ __launch_bounds__(256) void k_prep_hist(const float* __restrict__ wq,
                                                   const float* __restrict__ bq,
                                                   const float* __restrict__ wk,
                                                   const float* __restrict__ bk,
                                                   const float* __restrict__ wv,
                                                   const float* __restrict__ bv,
                                                   const float* __restrict__ we,
                                                   const float* __restrict__ be,
                                                   const float* __restrict__ wo,
                                                   const int* __restrict__ ei,
                                                   __half* __restrict__ WT,
                                                   __half* __restrict__ woT,
                                                   float* __restrict__ bias_all,
                                                   int* __restrict__ hist) {
  if (blockIdx.x >= PREP_NBLK) {
    const int e = (blockIdx.x - PREP_NBLK) * 256 + threadIdx.x;
    if (e < NE) atomicAdd(&hist[ei[e]], 1);
    return;
  }
  int idx = blockIdx.x * 256 + threadIdx.x;
  if (idx < NWT * ND) {
    const int n = idx >> 7, k = idx & 127;
    float v;
    if (n < 128)      v = wq[k * ND + n];
    else if (n < 256) v = wk[k * ND + (n - 128)];
    else if (n < 384) v = wv[k * ND + (n - 256)];
    else if (n < 896) {
      const int col = n - 384, h = col >> 6, j = col & 63;
      const float4* a = (const float4*)(wq + (size_t)k * ND + h * DK);
      const float4* b = (const float4*)(we + (size_t)j * ND + h * DK);
      float s = 0.f;
#pragma unroll
      for (int i = 0; i < 4; ++i) {
        float4 av = a[i], bv4 = b[i];
        s = fmaf(av.x, bv4.x, s); s = fmaf(av.y, bv4.y, s);
        s = fmaf(av.z, bv4.z, s); s = fmaf(av.w, bv4.w, s);
      }
      v = 0.25f * s;
    } else if (n < 904) {
      const int h = n - 896;
      const float4* a = (const float4*)(wq + (size_t)k * ND + h * DK);
      const float4* b = (const float4*)(be + h * DK);
      float s = 0.f;
#pragma unroll
      for (int i = 0; i < 4; ++i) {
        float4 av = a[i], bv4 = b[i];
        s = fmaf(av.x, bv4.x, s); s = fmaf(av.y, bv4.y, s);
        s = fmaf(av.z, bv4.z, s); s = fmaf(av.w, bv4.w, s);
      }
      v = 0.25f * s;
    } else v = 0.f;
    WT[idx] = __float2half_rn(v);
    return;
  }
  idx -= NWT * ND;
  if (idx < ND * ND) {
    const int n = idx >> 7, k = idx & 127;
    woT[idx] = __float2half_rn(wo[k * ND + n]);
    return;
  }
  idx -= ND * ND;
  if (idx < NWT) {
    float v;
    if (idx < 128)      v = bq[idx];
    else if (idx < 256) v = bk[idx - 128];
    else if (idx < 384) v = bv[idx - 256];
    else if (idx < 896) {
      const int col = idx - 384, h = col >> 6, j = col & 63;
      const float4* a = (const float4*)(bq + h * DK);
      const float4* b = (const float4*)(we + (size_t)j * ND + h * DK);
      float s = 0.f;
#pragma unroll
      for (int i = 0; i < 4; ++i) {
        float4 av = a[i], bv4 = b[i];
        s = fmaf(av.x, bv4.x, s); s = fmaf(av.y, bv4.y, s);
        s = fmaf(av.z, bv4.z, s); s = fmaf(av.w, bv4.w, s);
      }
      v = 0.25f * s;
    } else if (idx < 904) {
      const int h = idx - 896;
      const float4* a = (const float4*)(bq + h * DK);
      const float4* b = (const float4*)(be + h * DK);
      float s = 0.f;
#pragma unroll
      for (int i = 0; i < 4; ++i) {
        float4 av = a[i], bv4 = b[i];
        s = fmaf(av.x, bv4.x, s); s = fmaf(av.y, bv4.y, s);
        s = fmaf(av.z, bv4.z, s); s = fmaf(av.w, bv4.w, s);
      }
      v = 0.25f * s;
    } else v = 0.f;
    bias_all[idx] = v;
  }
}

// ---- MFMA GEMM 1: x(f32->f16) @ WT^T + bias -> qh|K16|V16, G16, SB ----
__global__ __launch_bounds__(256) void k_gemm1(const float* __restrict__ x,
                                               const __half* __restrict__ WT,
                                               const float* __restrict__ bias_all,
                                               __half* __restrict__ qh,
                                               __half* __restrict__ K16,
                                               __half* __restrict__ V16,
                                               __half* __restrict__ G16,
                                               float* __restrict__ SB) {
  __shared__ _Float16 bs[4][16][132];
  const int wave = threadIdx.x >> 6;
  const int l    = threadIdx.x & 63;
  const int row  = l & 15;
  const int kq   = l >> 4;
  const int r0   = blockIdx.x * 64 + wave * 16;

  f16x8 a[4];
#pragma unroll
  for (int s = 0; s < 4; ++s) {
    const float4* ap = (const float4*)(x + (size_t)(r0 + row) * ND + s * 32 + kq * 8);
    const float4 f0 = ap[0], f1 = ap[1];
    f16x8 t;
    t[0] = (_Float16)f0.x; t[1] = (_Float16)f0.y; t[2] = (_Float16)f0.z; t[3] = (_Float16)f0.w;
    t[4] = (_Float16)f1.x; t[5] = (_Float16)f1.y; t[6] = (_Float16)f1.z; t[7] = (_Float16)f1.w;
    a[s] = t;
  }

  const int rb = r0 + kq * 4;

  for (int nc = 0; nc < 56; nc += 4) {
    __syncthreads();
    {
      const __half* src = WT + (size_t)((nc + wave) * 16 + row) * ND;
      _Float16* dst = &bs[wave][row][0];
#pragma unroll
      for (int ch = 0; ch < 4; ++ch) {
        const int o = (kq + ch * 4) * 8;
        *(f16x8*)(dst + o) = *(const f16x8*)(src + o);
      }
    }
    __syncthreads();
#pragma unroll
    for (int t = 0; t < 4; ++t) {
      const int nt = nc + t;
      f32x4 c = {0.f, 0.f, 0.f, 0.f};
#pragma unroll
      for (int s = 0; s < 4; ++s) {
        const f16x8 b = *(const f16x8*)&bs[t][row][s * 32 + kq * 8];
        c = __builtin_amdgcn_mfma_f32_16x16x32_f16(a[s], b, c, 0, 0, 0);
      }
      const int col = nt * 16 + row;
      const float bb = bias_all[col];
      if (nt < 24) {
        __half* dst = (nt < 8) ? (qh + col) : (nt < 16) ? (K16 + (col - 128)) : (V16 + (col - 256));
#pragma unroll
        for (int i = 0; i < 4; ++i)
          dst[(size_t)(rb + i) * ND] = __float2half_rn(c[i] + bb);
      } else {
        const int gcol = col - 384;
#pragma unroll
        for (int i = 0; i < 4; ++i)
          G16[(size_t)(rb + i) * 512 + gcol] = __float2half_rn(c[i] + bb);
      }
    }
  }

  {
    f32x4 c = {0.f, 0.f, 0.f, 0.f};
#pragma unroll
    for (int s = 0; s < 4; ++s) {
      const f16x8 b = *(const f16x8*)(WT + (size_t)(896 + row) * ND + s * 32 + kq * 8);
      c = __builtin_amdgcn_mfma_f32_16x16x32_f16(a[s], b, c, 0, 0, 0);
    }
    if (row < 8) {
      const float bb = bias_all[896 + row];
#pragma unroll
      for (int i = 0; i < 4; ++i)
        SB[(size_t)(rb + i) * NH + row] = c[i] + bb;
    }
  }
}

// ---- MFMA GEMM 2: mh(f16) @ woT^T + bo -> out(f32); woT fully LDS-staged ----
__global__ __launch_bounds__(256) void k_gemm2(const __half* __restrict__ mh,
                                               const __half* __restrict__ woT,
                                               const float* __restrict__ bo,
                                               float* __restrict__ out) {
  __shared__ _Float16 ws[128][132];
  const int tid  = threadIdx.x;
  const int wave = tid >> 6;
  const int l    = tid & 63;
  const int row  = l & 15;
  const int kq   = l >> 4;
  const int r0   = blockIdx.x * 64 + wave * 16;

  {
    const int r = tid & 127, hf = tid >> 7;
    const __half* src = woT + (size_t)r * ND + hf * 64;
    _Float16* dst = &ws[r][hf * 64];
#pragma unroll
    for (int ch = 0; ch < 8; ++ch)
      *(f16x8*)(dst + ch * 8) = *(const f16x8*)(src + ch * 8);
  }

  f16x8 a[4];
#pragma unroll
  for (int s = 0; s < 4; ++s)
    a[s] = *(const f16x8*)(mh + (size_t)(r0 + row) * ND + s * 32 + kq * 8);

  __syncthreads();

  const int rb = r0 + kq * 4;
#pragma unroll 2
  for (int nt = 0; nt < 8; ++nt) {
    f32x4 c = {0.f, 0.f, 0.f, 0.f};
#pragma unroll
    for (int s = 0; s < 4; ++s) {
      const f16x8 b = *(const f16x8*)&ws[nt * 16 + row][s * 32 + kq * 8];
      c = __builtin_amdgcn_mfma_f32_16x16x32_f16(a[s], b, c, 0, 0, 0);
    }
    const int col = nt * 16 + row;
    const float bb = bo[col];
#pragma unroll
    for (int i = 0; i < 4; ++i)
      out[(size_t)(rb + i) * ND + col] = c[i] + bb;
  }
}

// ---------------- CSR scans + scatter ----------------
__global__ __launch_bounds__(256) void k_scan1(const int* __restrict__ hist,
                                               int* __restrict__ off,
                                               int* __restrict__ bsum) {
  __shared__ int sh[256];
  const int tid = threadIdx.x;
  const int idx = blockIdx.x * 256 + tid;
  int v = (idx < NN) ? hist[idx] : 0;
  sh[tid] = v;
  __syncthreads();
#pragma unroll
  for (int d = 1; d < 256; d <<= 1) {
    int t = (tid >= d) ? sh[tid - d] : 0;
    __syncthreads();
    sh[tid] += t;
    __syncthreads();
  }
  if (idx < NN) off[idx] = sh[tid] - v;
  if (tid == 255) bsum[blockIdx.x] = sh[255];
}

__global__ __launch_bounds__(256) void k_scan2(int* __restrict__ bsum) {
  __shared__ int sh[256];
  const int tid = threadIdx.x;
  int v = (tid < SCAN_NBLK) ? bsum[tid] : 0;
  sh[tid] = v;
  __syncthreads();
#pragma unroll
  for (int d = 1; d < 256; d <<= 1) {
    int t = (tid >= d) ? sh[tid - d] : 0;
    __syncthreads();
    sh[tid] += t;
    __syncthreads();
  }
  if (tid < SCAN_NBLK) bsum[tid] = sh[tid] - v;
}

__global__ __launch_bounds__(256) void k_scan3(int* __restrict__ off,
                                               const int* __restrict__ bsum,
                                               int* __restrict__ cursor) {
  const int idx = blockIdx.x * 256 + threadIdx.x;
  if (idx < NN) {
    int o = off[idx] + bsum[blockIdx.x];
    off[idx] = o;
    cursor[idx] = o;
  }
  if (blockIdx.x == 0 && threadIdx.x == 0) off[NN] = NE;
}

__global__ __launch_bounds__(256) void k_scatter(const int* __restrict__ ei,
                                                 int* __restrict__ cursor,
                                                 int2* __restrict__ pair) {
  int e = blockIdx.x * 256 + threadIdx.x;
  if (e >= NE) return;
  int row = ei[e];
  int col = ei[NE + e];
  int pos = atomicAdd(&cursor[row], 1);
  pair[pos] = make_int2(col, e);
}

// ---------------- fused gather (R14 topology + chunk-wide K/V load hoist) ----
// 8 nodes/block, 32 lanes/node, chunk = 8 edges. Per chunk:
//   1. extract 8 cols, issue ALL 16 K/V loads (raw f16x4 in regs)
//   2. ds_write ea(t); prefetch ea(t+1)->regs + pair(t+2)
//   3. lgkmcnt(0); compute 8 edges from preloaded kz/vz + LDS ea
__global__ __launch_bounds__(256) void k_gather(const __half* __restrict__ qh,
                                                const __half* __restrict__ K16,
                                                const __half* __restrict__ V16,
                                                const float* __restrict__ ea,
                                                const int* __restrict__ off,
                                                const int2* __restrict__ pair,
                                                const __half* __restrict__ G16,
                                                const float* __restrict__ SB,
                                                __half* __restrict__ mh) {
  __shared__ float eas[8][8 * ED];   // 16 KB/block
  const int g = threadIdx.x >> 5;
  const int n = blockIdx.x * 8 + g;
  const int l = threadIdx.x & 31;
  const int h = l >> 2;
  const int q = l & 3;

  float gg[16];
  float4 qv;
  {
    const __half2* qp2 = (const __half2*)(qh + (size_t)n * ND + h * DK + q * 4);
    float2 q01 = __half22float2(qp2[0]);
    float2 q23 = __half22float2(qp2[1]);
    qv.x = q01.x * 0.25f; qv.y = q01.y * 0.25f;
    qv.z = q23.x * 0.25f; qv.w = q23.y * 0.25f;
  }
  const float sb = SB[n * NH + h];   // already x0.25
  {
    const float4* gp = (const float4*)(G16 + (size_t)n * 512 + h * 64 + q * 16);
    float4 c0 = gp[0], c1 = gp[1];
    const __half2* h0 = (const __half2*)&c0;
    const __half2* h1 = (const __half2*)&c1;
#pragma unroll
    for (int i = 0; i < 4; ++i) {
      float2 f0 = __half22float2(h0[i]);
      gg[2 * i + 0] = f0.x; gg[2 * i + 1] = f0.y;
      float2 f1 = __half22float2(h1[i]);
      gg[8 + 2 * i + 0] = f1.x; gg[8 + 2 * i + 1] = f1.y;
    }
  }

  float4 acc = make_float4(0.f, 0.f, 0.f, 0.f);
  float den = 0.f;

  const int j0 = off[n], j1 = off[n + 1];
  const int jlast = j1 - 1;
  const int hq = h * DK + q * 4;
  const int l8 = l & 7;
  const int se = l >> 2;   // staging edge 0..7
  const int sp = l & 3;    // staging float4-part

  if (j0 < j1) {
    int2 p = pair[min(j0 + l8, jlast)];
    float4 er0, er1, er2, er3;
    {
      const int eid = __shfl(p.y, se, 32);
      const float4* s4 = (const float4*)(ea + (size_t)eid * ED) + sp;
      er0 = s4[0]; er1 = s4[4]; er2 = s4[8]; er3 = s4[12];
    }
    int2 pn = pair[min(j0 + 8 + l8, jlast)];

    for (int jp = j0; jp < j1; jp += 8) {
      // 1. extract cols and issue ALL chunk K/V loads up-front
      int cols[8];
#pragma unroll
      for (int c = 0; c < 8; ++c) cols[c] = __shfl(p.x, c, 32);
      float2 kz[8], vz[8];
#pragma unroll
      for (int c = 0; c < 8; ++c) {
        kz[c] = *(const float2*)(K16 + (size_t)cols[c] * ND + hq);
        vz[c] = *(const float2*)(V16 + (size_t)cols[c] * ND + hq);
      }

      // 2. ds_write ea(t)
      {
        float* d = &eas[g][se * ED] + sp * 4;
        *(float4*)(d + 0)  = er0; *(float4*)(d + 16) = er1;
        *(float4*)(d + 32) = er2; *(float4*)(d + 48) = er3;
      }
      // prefetch ea(t+1) regs + pair(t+2)
      int2 pf = pn;
      if (jp + 8 < j1) {
        const int eidN = __shfl(pn.y, se, 32);
        const float4* s4 = (const float4*)(ea + (size_t)eidN * ED) + sp;
        er0 = s4[0]; er1 = s4[4]; er2 = s4[8]; er3 = s4[12];
        pf = pair[min(jp + 16 + l8, jlast)];
      }

      // 3. staging visible to the 32-group
      asm volatile("s_waitcnt lgkmcnt(0)" ::: "memory");
      __builtin_amdgcn_sched_barrier(0);

      // compute 8 edges from preloaded kz/vz + LDS ea
#pragma unroll
      for (int c = 0; c < 8; ++c) {
        const __half2* kh = (const __half2*)&kz[c];
        const float2 ka = __half22float2(kh[0]);
        const float2 kb = __half22float2(kh[1]);

        float s = ka.x * qv.x;
        s = fmaf(qv.y, ka.y, s); s = fmaf(qv.z, kb.x, s); s = fmaf(qv.w, kb.y, s);

        const float4* ep = (const float4*)&eas[g][c * ED + q * 16];
#pragma unroll
        for (int i = 0; i < 4; ++i) {
          float4 a = ep[i];
          s = fmaf(a.x, gg[4 * i + 0], s); s = fmaf(a.y, gg[4 * i + 1], s);
          s = fmaf(a.z, gg[4 * i + 2], s); s = fmaf(a.w, gg[4 * i + 3], s);
        }

        s += __shfl_xor(s, 1); s += __shfl_xor(s, 2);
        const float es = (jp + c < j1) ? __expf(s + sb) : 0.f;
        den += es;

        const __half2* vh = (const __half2*)&vz[c];
        const float2 va = __half22float2(vh[0]);
        const float2 vb = __half22float2(vh[1]);
        acc.x = fmaf(es, va.x, acc.x); acc.y = fmaf(es, va.y, acc.y);
        acc.z = fmaf(es, vb.x, acc.z); acc.w = fmaf(es, vb.y, acc.w);
      }

      p = pn; pn = pf;
    }
  }

  const float inv = 1.f / (den + 1e-8f);
  union { __half2 h2[2]; float2 f; } u;
  u.h2[0] = __floats2half2_rn(acc.x * inv, acc.y * inv);
  u.h2[1] = __floats2half2_rn(acc.z * inv, acc.w * inv);
  *(float2*)(mh + (size_t)n * ND + h * DK + q * 4) = u.f;
}

extern "C" void kernel_launch(void* const* d_in, const int* in_sizes, int n_in,
                              void* d_out, int out_size, void* d_ws, size_t ws_size,
                              hipStream_t stream) {
  const float* nodes = (const float*)d_in[0];
  const int*   ei    = (const int*)d_in[1];
  const float* ea    = (const float*)d_in[2];
  const float* wq    = (const float*)d_in[3];
  const float* bq    = (const float*)d_in[4];
  const float* wk    = (const float*)d_in[5];
  const float* bk    = (const float*)d_in[6];
  const float* wv    = (const float*)d_in[7];
  const float* bv    = (const float*)d_in[8];
  const float* we    = (const float*)d_in[9];
  const float* be    = (const float*)d_in[10];
  const float* wo    = (const float*)d_in[11];
  const float* bo    = (const float*)d_in[12];
  float* out = (float*)d_out;

  const size_t NND = (size_t)NN * ND;
  __half* qh   = (__half*)d_ws;              // NND
  __half* K16  = qh + NND;                   // NND
  __half* V16  = K16 + NND;                  // NND
  __half* mh   = V16 + NND;                  // NND
  __half* G16  = mh + NND;                   // NN*512
  __half* WT   = G16 + (size_t)NN * 512;     // 912*128
  __half* woT  = WT + (size_t)NWT * ND;      // 128*128
  float* SB    = (float*)(woT + ND * ND);    // NN*8
  float* bias_all = SB + (size_t)NN * NH;    // NWT
  int* hist    = (int*)(bias_all + NWT);     // NN
  int* off     = hist + NN;                  // 40004
  int* cursor  = off + 40004;                // NN
  int* bsum    = cursor + NN;                // 256
  int2* pair   = (int2*)(bsum + 256);        // NE

  hipMemsetAsync(hist, 0, NN * sizeof(int), stream);

  dim3 blk(256);

  k_prep_hist<<<dim3(PREP_NBLK + (NE + 255) / 256), blk, 0, stream>>>(
      wq, bq, wk, bk, wv, bv, we, be, wo, ei, WT, woT, bias_all, hist);

  k_gemm1<<<dim3(NN / 64), blk, 0, stream>>>(nodes, WT, bias_all, qh, K16, V16, G16, SB);

  k_scan1<<<dim3(SCAN_NBLK), blk, 0, stream>>>(hist, off, bsum);
  k_scan2<<<dim3(1), blk, 0, stream>>>(bsum);
  k_scan3<<<dim3(SCAN_NBLK), blk, 0, stream>>>(off, bsum, cursor);
  dim3 gE((NE + 255) / 256);
  k_scatter<<<gE, blk, 0, stream>>>(ei, cursor, pair);

  k_gather<<<dim3(NN / 8), blk, 0, stream>>>(qh, K16, V16, ea, off, pair, G16, SB, mh);

  k_gemm2<<<dim3(NN / 64), blk, 0, stream>>>(mh, woT, bo, out);
}

// Round 18
// 183.961 us; speedup vs baseline: 3.6246x; 1.1379x over previous
//
#include <hip/hip_runtime.h>
#include <hip/hip_fp16.h>

#define NN  40000
#define NE  640000
#define ND  128
#define ED  64
#define NH  8
#define DK  16
#define NWT 912   // 384 (q|k|v) + 512 (G composed) + 16 (SB rows, 8 used)

#define SCAN_NBLK 157   // ceil(40000/256)
#define PREP_NBLK 524   // ceil((NWT*ND + ND*ND + NWT)/256)
#define GEMM1_NBLK 625  // NN/64

typedef _Float16 f16x8 __attribute__((ext_vector_type(8)));
typedef float    f32x4 __attribute__((ext_vector_type(4)));

// ---- prep (WT/woT/bias compose) + hist, merged into one launch ----
__global__ __launch_bounds__(256) void k_prep_hist(const float* __restrict__ wq,
                                                   const float* __restrict__ bq,
                                                   const float* __restrict__ wk,
                                                   const float* __restrict__ bk,
                                                   const float* __restrict__ wv,
                                                   const float* __restrict__ bv,
                                                   const float* __restrict__ we,
                                                   const float* __restrict__ be,
                                                   const float* __restrict__ wo,
                                                   const int* __restrict__ ei,
                                                   __half* __restrict__ WT,
                                                   __half* __restrict__ woT,
                                                   float* __restrict__ bias_all,
                                                   int* __restrict__ hist) {
  if (blockIdx.x >= PREP_NBLK) {
    const int e = (blockIdx.x - PREP_NBLK) * 256 + threadIdx.x;
    if (e < NE) atomicAdd(&hist[ei[e]], 1);
    return;
  }
  int idx = blockIdx.x * 256 + threadIdx.x;
  if (idx < NWT * ND) {
    const int n = idx >> 7, k = idx & 127;
    float v;
    if (n < 128)      v = wq[k * ND + n];
    else if (n < 256) v = wk[k * ND + (n - 128)];
    else if (n < 384) v = wv[k * ND + (n - 256)];
    else if (n < 896) {
      const int col = n - 384, h = col >> 6, j = col & 63;
      const float4* a = (const float4*)(wq + (size_t)k * ND + h * DK);
      const float4* b = (const float4*)(we + (size_t)j * ND + h * DK);
      float s = 0.f;
#pragma unroll
      for (int i = 0; i < 4; ++i) {
        float4 av = a[i], bv4 = b[i];
        s = fmaf(av.x, bv4.x, s); s = fmaf(av.y, bv4.y, s);
        s = fmaf(av.z, bv4.z, s); s = fmaf(av.w, bv4.w, s);
      }
      v = 0.25f * s;
    } else if (n < 904) {
      const int h = n - 896;
      const float4* a = (const float4*)(wq + (size_t)k * ND + h * DK);
      const float4* b = (const float4*)(be + h * DK);
      float s = 0.f;
#pragma unroll
      for (int i = 0; i < 4; ++i) {
        float4 av = a[i], bv4 = b[i];
        s = fmaf(av.x, bv4.x, s); s = fmaf(av.y, bv4.y, s);
        s = fmaf(av.z, bv4.z, s); s = fmaf(av.w, bv4.w, s);
      }
      v = 0.25f * s;
    } else v = 0.f;
    WT[idx] = __float2half_rn(v);
    return;
  }
  idx -= NWT * ND;
  if (idx < ND * ND) {
    const int n = idx >> 7, k = idx & 127;
    woT[idx] = __float2half_rn(wo[k * ND + n]);
    return;
  }
  idx -= ND * ND;
  if (idx < NWT) {
    float v;
    if (idx < 128)      v = bq[idx];
    else if (idx < 256) v = bk[idx - 128];
    else if (idx < 384) v = bv[idx - 256];
    else if (idx < 896) {
      const int col = idx - 384, h = col >> 6, j = col & 63;
      const float4* a = (const float4*)(bq + h * DK);
      const float4* b = (const float4*)(we + (size_t)j * ND + h * DK);
      float s = 0.f;
#pragma unroll
      for (int i = 0; i < 4; ++i) {
        float4 av = a[i], bv4 = b[i];
        s = fmaf(av.x, bv4.x, s); s = fmaf(av.y, bv4.y, s);
        s = fmaf(av.z, bv4.z, s); s = fmaf(av.w, bv4.w, s);
      }
      v = 0.25f * s;
    } else if (idx < 904) {
      const int h = idx - 896;
      const float4* a = (const float4*)(bq + h * DK);
      const float4* b = (const float4*)(be + h * DK);
      float s = 0.f;
#pragma unroll
      for (int i = 0; i < 4; ++i) {
        float4 av = a[i], bv4 = b[i];
        s = fmaf(av.x, bv4.x, s); s = fmaf(av.y, bv4.y, s);
        s = fmaf(av.z, bv4.z, s); s = fmaf(av.w, bv4.w, s);
      }
      v = 0.25f * s;
    } else v = 0.f;
    bias_all[idx] = v;
  }
}

// ---- fused: MFMA GEMM 1 (blocks 0..624) + CSR scatter (blocks 625..3124) ----
// Independent workloads co-scheduled in one dispatch: MFMA-bound GEMM overlaps
// the atomic/memory-bound scatter instead of serializing behind it.
__global__ __launch_bounds__(256) void k_gemm1_scatter(const float* __restrict__ x,
                                                       const __half* __restrict__ WT,
                                                       const float* __restrict__ bias_all,
                                                       const int* __restrict__ ei,
                                                       int* __restrict__ cursor,
                                                       int2* __restrict__ pair,
                                                       __half* __restrict__ qh,
                                                       __half* __restrict__ K16,
                                                       __half* __restrict__ V16,
                                                       __half* __restrict__ G16,
                                                       float* __restrict__ SB) {
  __shared__ _Float16 bs[4][16][132];

  if (blockIdx.x >= GEMM1_NBLK) {
    // ---------- scatter ----------
    const int e = (blockIdx.x - GEMM1_NBLK) * 256 + threadIdx.x;
    if (e < NE) {
      const int row = ei[e];
      const int col = ei[NE + e];
      const int pos = atomicAdd(&cursor[row], 1);
      pair[pos] = make_int2(col, e);
    }
    return;
  }

  // ---------- gemm1 ----------
  const int wave = threadIdx.x >> 6;
  const int l    = threadIdx.x & 63;
  const int row  = l & 15;
  const int kq   = l >> 4;
  const int r0   = blockIdx.x * 64 + wave * 16;

  f16x8 a[4];
#pragma unroll
  for (int s = 0; s < 4; ++s) {
    const float4* ap = (const float4*)(x + (size_t)(r0 + row) * ND + s * 32 + kq * 8);
    const float4 f0 = ap[0], f1 = ap[1];
    f16x8 t;
    t[0] = (_Float16)f0.x; t[1] = (_Float16)f0.y; t[2] = (_Float16)f0.z; t[3] = (_Float16)f0.w;
    t[4] = (_Float16)f1.x; t[5] = (_Float16)f1.y; t[6] = (_Float16)f1.z; t[7] = (_Float16)f1.w;
    a[s] = t;
  }

  const int rb = r0 + kq * 4;

  for (int nc = 0; nc < 56; nc += 4) {
    __syncthreads();
    {
      const __half* src = WT + (size_t)((nc + wave) * 16 + row) * ND;
      _Float16* dst = &bs[wave][row][0];
#pragma unroll
      for (int ch = 0; ch < 4; ++ch) {
        const int o = (kq + ch * 4) * 8;
        *(f16x8*)(dst + o) = *(const f16x8*)(src + o);
      }
    }
    __syncthreads();
#pragma unroll
    for (int t = 0; t < 4; ++t) {
      const int nt = nc + t;
      f32x4 c = {0.f, 0.f, 0.f, 0.f};
#pragma unroll
      for (int s = 0; s < 4; ++s) {
        const f16x8 b = *(const f16x8*)&bs[t][row][s * 32 + kq * 8];
        c = __builtin_amdgcn_mfma_f32_16x16x32_f16(a[s], b, c, 0, 0, 0);
      }
      const int col = nt * 16 + row;
      const float bb = bias_all[col];
      if (nt < 24) {
        __half* dst = (nt < 8) ? (qh + col) : (nt < 16) ? (K16 + (col - 128)) : (V16 + (col - 256));
#pragma unroll
        for (int i = 0; i < 4; ++i)
          dst[(size_t)(rb + i) * ND] = __float2half_rn(c[i] + bb);
      } else {
        const int gcol = col - 384;
#pragma unroll
        for (int i = 0; i < 4; ++i)
          G16[(size_t)(rb + i) * 512 + gcol] = __float2half_rn(c[i] + bb);
      }
    }
  }

  {
    f32x4 c = {0.f, 0.f, 0.f, 0.f};
#pragma unroll
    for (int s = 0; s < 4; ++s) {
      const f16x8 b = *(const f16x8*)(WT + (size_t)(896 + row) * ND + s * 32 + kq * 8);
      c = __builtin_amdgcn_mfma_f32_16x16x32_f16(a[s], b, c, 0, 0, 0);
    }
    if (row < 8) {
      const float bb = bias_all[896 + row];
#pragma unroll
      for (int i = 0; i < 4; ++i)
        SB[(size_t)(rb + i) * NH + row] = c[i] + bb;
    }
  }
}

// ---- MFMA GEMM 2: mh(f16) @ woT^T + bo -> out(f32); woT fully LDS-staged ----
__global__ __launch_bounds__(256) void k_gemm2(const __half* __restrict__ mh,
                                               const __half* __restrict__ woT,
                                               const float* __restrict__ bo,
                                               float* __restrict__ out) {
  __shared__ _Float16 ws[128][132];
  const int tid  = threadIdx.x;
  const int wave = tid >> 6;
  const int l    = tid & 63;
  const int row  = l & 15;
  const int kq   = l >> 4;
  const int r0   = blockIdx.x * 64 + wave * 16;

  {
    const int r = tid & 127, hf = tid >> 7;
    const __half* src = woT + (size_t)r * ND + hf * 64;
    _Float16* dst = &ws[r][hf * 64];
#pragma unroll
    for (int ch = 0; ch < 8; ++ch)
      *(f16x8*)(dst + ch * 8) = *(const f16x8*)(src + ch * 8);
  }

  f16x8 a[4];
#pragma unroll
  for (int s = 0; s < 4; ++s)
    a[s] = *(const f16x8*)(mh + (size_t)(r0 + row) * ND + s * 32 + kq * 8);

  __syncthreads();

  const int rb = r0 + kq * 4;
#pragma unroll 2
  for (int nt = 0; nt < 8; ++nt) {
    f32x4 c = {0.f, 0.f, 0.f, 0.f};
#pragma unroll
    for (int s = 0; s < 4; ++s) {
      const f16x8 b = *(const f16x8*)&ws[nt * 16 + row][s * 32 + kq * 8];
      c = __builtin_amdgcn_mfma_f32_16x16x32_f16(a[s], b, c, 0, 0, 0);
    }
    const int col = nt * 16 + row;
    const float bb = bo[col];
#pragma unroll
    for (int i = 0; i < 4; ++i)
      out[(size_t)(rb + i) * ND + col] = c[i] + bb;
  }
}

// ---------------- CSR scans ----------------
__global__ __launch_bounds__(256) void k_scan1(const int* __restrict__ hist,
                                               int* __restrict__ off,
                                               int* __restrict__ bsum) {
  __shared__ int sh[256];
  const int tid = threadIdx.x;
  const int idx = blockIdx.x * 256 + tid;
  int v = (idx < NN) ? hist[idx] : 0;
  sh[tid] = v;
  __syncthreads();
#pragma unroll
  for (int d = 1; d < 256; d <<= 1) {
    int t = (tid >= d) ? sh[tid - d] : 0;
    __syncthreads();
    sh[tid] += t;
    __syncthreads();
  }
  if (idx < NN) off[idx] = sh[tid] - v;
  if (tid == 255) bsum[blockIdx.x] = sh[255];
}

__global__ __launch_bounds__(256) void k_scan2(int* __restrict__ bsum) {
  __shared__ int sh[256];
  const int tid = threadIdx.x;
  int v = (tid < SCAN_NBLK) ? bsum[tid] : 0;
  sh[tid] = v;
  __syncthreads();
#pragma unroll
  for (int d = 1; d < 256; d <<= 1) {
    int t = (tid >= d) ? sh[tid - d] : 0;
    __syncthreads();
    sh[tid] += t;
    __syncthreads();
  }
  if (tid < SCAN_NBLK) bsum[tid] = sh[tid] - v;
}

__global__ __launch_bounds__(256) void k_scan3(int* __restrict__ off,
                                               const int* __restrict__ bsum,
                                               int* __restrict__ cursor) {
  const int idx = blockIdx.x * 256 + threadIdx.x;
  if (idx < NN) {
    int o = off[idx] + bsum[blockIdx.x];
    off[idx] = o;
    cursor[idx] = o;
  }
  if (blockIdx.x == 0 && threadIdx.x == 0) off[NN] = NE;
}

// ---------------- fused gather (R17 + setprio around compute) ----------------
__global__ __launch_bounds__(256) void k_gather(const __half* __restrict__ qh,
                                                const __half* __restrict__ K16,
                                                const __half* __restrict__ V16,
                                                const float* __restrict__ ea,
                                                const int* __restrict__ off,
                                                const int2* __restrict__ pair,
                                                const __half* __restrict__ G16,
                                                const float* __restrict__ SB,
                                                __half* __restrict__ mh) {
  __shared__ float eas[8][8 * ED];   // 16 KB/block
  const int g = threadIdx.x >> 5;
  const int n = blockIdx.x * 8 + g;
  const int l = threadIdx.x & 31;
  const int h = l >> 2;
  const int q = l & 3;

  float gg[16];
  float4 qv;
  {
    const __half2* qp2 = (const __half2*)(qh + (size_t)n * ND + h * DK + q * 4);
    float2 q01 = __half22float2(qp2[0]);
    float2 q23 = __half22float2(qp2[1]);
    qv.x = q01.x * 0.25f; qv.y = q01.y * 0.25f;
    qv.z = q23.x * 0.25f; qv.w = q23.y * 0.25f;
  }
  const float sb = SB[n * NH + h];   // already x0.25
  {
    const float4* gp = (const float4*)(G16 + (size_t)n * 512 + h * 64 + q * 16);
    float4 c0 = gp[0], c1 = gp[1];
    const __half2* h0 = (const __half2*)&c0;
    const __half2* h1 = (const __half2*)&c1;
#pragma unroll
    for (int i = 0; i < 4; ++i) {
      float2 f0 = __half22float2(h0[i]);
      gg[2 * i + 0] = f0.x; gg[2 * i + 1] = f0.y;
      float2 f1 = __half22float2(h1[i]);
      gg[8 + 2 * i + 0] = f1.x; gg[8 + 2 * i + 1] = f1.y;
    }
  }

  float4 acc = make_float4(0.f, 0.f, 0.f, 0.f);
  float den = 0.f;

  const int j0 = off[n], j1 = off[n + 1];
  const int jlast = j1 - 1;
  const int hq = h * DK + q * 4;
  const int l8 = l & 7;
  const int se = l >> 2;   // staging edge 0..7
  const int sp = l & 3;    // staging float4-part

  if (j0 < j1) {
    int2 p = pair[min(j0 + l8, jlast)];
    float4 er0, er1, er2, er3;
    {
      const int eid = __shfl(p.y, se, 32);
      const float4* s4 = (const float4*)(ea + (size_t)eid * ED) + sp;
      er0 = s4[0]; er1 = s4[4]; er2 = s4[8]; er3 = s4[12];
    }
    int2 pn = pair[min(j0 + 8 + l8, jlast)];

    for (int jp = j0; jp < j1; jp += 8) {
      // 1. extract cols and issue ALL chunk K/V loads up-front
      int cols[8];
#pragma unroll
      for (int c = 0; c < 8; ++c) cols[c] = __shfl(p.x, c, 32);
      float2 kz[8], vz[8];
#pragma unroll
      for (int c = 0; c < 8; ++c) {
        kz[c] = *(const float2*)(K16 + (size_t)cols[c] * ND + hq);
        vz[c] = *(const float2*)(V16 + (size_t)cols[c] * ND + hq);
      }

      // 2. ds_write ea(t)
      {
        float* d = &eas[g][se * ED] + sp * 4;
        *(float4*)(d + 0)  = er0; *(float4*)(d + 16) = er1;
        *(float4*)(d + 32) = er2; *(float4*)(d + 48) = er3;
      }
      // prefetch ea(t+1) regs + pair(t+2)
      int2 pf = pn;
      if (jp + 8 < j1) {
        const int eidN = __shfl(pn.y, se, 32);
        const float4* s4 = (const float4*)(ea + (size_t)eidN * ED) + sp;
        er0 = s4[0]; er1 = s4[4]; er2 = s4[8]; er3 = s4[12];
        pf = pair[min(jp + 16 + l8, jlast)];
      }

      // 3. staging visible to the 32-group
      asm volatile("s_waitcnt lgkmcnt(0)" ::: "memory");
      __builtin_amdgcn_sched_barrier(0);

      // compute 8 edges from preloaded kz/vz + LDS ea (prio-boosted)
      __builtin_amdgcn_s_setprio(1);
#pragma unroll
      for (int c = 0; c < 8; ++c) {
        const __half2* kh = (const __half2*)&kz[c];
        const float2 ka = __half22float2(kh[0]);
        const float2 kb = __half22float2(kh[1]);

        float s = ka.x * qv.x;
        s = fmaf(qv.y, ka.y, s); s = fmaf(qv.z, kb.x, s); s = fmaf(qv.w, kb.y, s);

        const float4* ep = (const float4*)&eas[g][c * ED + q * 16];
#pragma unroll
        for (int i = 0; i < 4; ++i) {
          float4 a = ep[i];
          s = fmaf(a.x, gg[4 * i + 0], s); s = fmaf(a.y, gg[4 * i + 1], s);
          s = fmaf(a.z, gg[4 * i + 2], s); s = fmaf(a.w, gg[4 * i + 3], s);
        }

        s += __shfl_xor(s, 1); s += __shfl_xor(s, 2);
        const float es = (jp + c < j1) ? __expf(s + sb) : 0.f;
        den += es;

        const __half2* vh = (const __half2*)&vz[c];
        const float2 va = __half22float2(vh[0]);
        const float2 vb = __half22float2(vh[1]);
        acc.x = fmaf(es, va.x, acc.x); acc.y = fmaf(es, va.y, acc.y);
        acc.z = fmaf(es, vb.x, acc.z); acc.w = fmaf(es, vb.y, acc.w);
      }
      __builtin_amdgcn_s_setprio(0);

      p = pn; pn = pf;
    }
  }

  const float inv = 1.f / (den + 1e-8f);
  union { __half2 h2[2]; float2 f; } u;
  u.h2[0] = __floats2half2_rn(acc.x * inv, acc.y * inv);
  u.h2[1] = __floats2half2_rn(acc.z * inv, acc.w * inv);
  *(float2*)(mh + (size_t)n * ND + h * DK + q * 4) = u.f;
}

extern "C" void kernel_launch(void* const* d_in, const int* in_sizes, int n_in,
                              void* d_out, int out_size, void* d_ws, size_t ws_size,
                              hipStream_t stream) {
  const float* nodes = (const float*)d_in[0];
  const int*   ei    = (const int*)d_in[1];
  const float* ea    = (const float*)d_in[2];
  const float* wq    = (const float*)d_in[3];
  const float* bq    = (const float*)d_in[4];
  const float* wk    = (const float*)d_in[5];
  const float* bk    = (const float*)d_in[6];
  const float* wv    = (const float*)d_in[7];
  const float* bv    = (const float*)d_in[8];
  const float* we    = (const float*)d_in[9];
  const float* be    = (const float*)d_in[10];
  const float* wo    = (const float*)d_in[11];
  const float* bo    = (const float*)d_in[12];
  float* out = (float*)d_out;

  const size_t NND = (size_t)NN * ND;
  __half* qh   = (__half*)d_ws;              // NND
  __half* K16  = qh + NND;                   // NND
  __half* V16  = K16 + NND;                  // NND
  __half* mh   = V16 + NND;                  // NND
  __half* G16  = mh + NND;                   // NN*512
  __half* WT   = G16 + (size_t)NN * 512;     // 912*128
  __half* woT  = WT + (size_t)NWT * ND;      // 128*128
  float* SB    = (float*)(woT + ND * ND);    // NN*8
  float* bias_all = SB + (size_t)NN * NH;    // NWT
  int* hist    = (int*)(bias_all + NWT);     // NN
  int* off     = hist + NN;                  // 40004
  int* cursor  = off + 40004;                // NN
  int* bsum    = cursor + NN;                // 256
  int2* pair   = (int2*)(bsum + 256);        // NE

  hipMemsetAsync(hist, 0, NN * sizeof(int), stream);

  dim3 blk(256);

  k_prep_hist<<<dim3(PREP_NBLK + (NE + 255) / 256), blk, 0, stream>>>(
      wq, bq, wk, bk, wv, bv, we, be, wo, ei, WT, woT, bias_all, hist);

  k_scan1<<<dim3(SCAN_NBLK), blk, 0, stream>>>(hist, off, bsum);
  k_scan2<<<dim3(1), blk, 0, stream>>>(bsum);
  k_scan3<<<dim3(SCAN_NBLK), blk, 0, stream>>>(off, bsum, cursor);

  k_gemm1_scatter<<<dim3(GEMM1_NBLK + (NE + 255) / 256), blk, 0, stream>>>(
      nodes, WT, bias_all, ei, cursor, pair, qh, K16, V16, G16, SB);

  k_gather<<<dim3(NN / 8), blk, 0, stream>>>(qh, K16, V16, ea, off, pair, G16, SB, mh);

  k_gemm2<<<dim3(NN / 64), blk, 0, stream>>>(mh, woT, bo, out);
}